// Round 22
// baseline (271.813 us; speedup 1.0000x reference)
//
#include <hip/hip_runtime.h>
#include <hip/hip_bf16.h>
#include <cstdint>
#include <cstddef>

typedef __attribute__((ext_vector_type(4))) float f32x4;
typedef __attribute__((ext_vector_type(16))) float f32x16;
typedef __attribute__((ext_vector_type(8))) __bf16 bf16x8;

constexpr int Bc = 4, Sc = 2048, Dc = 1024, Hc = 16, HDc = 64;
constexpr int Mrows = Bc * Sc;   // 8192
constexpr int Kdim = Dc;         // 1024

__device__ __forceinline__ void gload_lds16(const void* g, void* lds) {
  __builtin_amdgcn_global_load_lds(
      (const __attribute__((address_space(1))) void*)g,
      (__attribute__((address_space(3))) void*)lds, 16, 0, 0);
}

// bare v_exp_f32 (= exp2) — numerically validated R13/R15/R20/R21. Inputs
// bounded above by defer-max; large-negative underflows to 0 (softmax).
__device__ __forceinline__ float exp2_fast(float x) {
  float r;
  asm("v_exp_f32 %0, %1" : "=v"(r) : "v"(x));
  return r;
}

// ---------------- fp32 -> bf16 weight converts (one fused launch) ----------------
__global__ void cvt4_f32_to_bf16(const float* __restrict__ s0, const float* __restrict__ s1,
                                 const float* __restrict__ s2, const float* __restrict__ s3,
                                 __bf16* __restrict__ d0, __bf16* __restrict__ d1,
                                 __bf16* __restrict__ d2, __bf16* __restrict__ d3, int n4each) {
  int i = blockIdx.x * blockDim.x + threadIdx.x;
  int which = i / n4each, j = i - which * n4each;
  const float* s = which == 0 ? s0 : which == 1 ? s1 : which == 2 ? s2 : s3;
  __bf16* d = which == 0 ? d0 : which == 1 ? d1 : which == 2 ? d2 : d3;
  float4 f = ((const float4*)s)[j];
  union { __bf16 h[4]; uint2 u; } p;
  p.h[0] = (__bf16)f.x; p.h[1] = (__bf16)f.y;
  p.h[2] = (__bf16)f.z; p.h[3] = (__bf16)f.w;
  ((uint2*)d)[j] = p.u;
}

// ---------------- fused QKV GEMM (R10-R21 proven) ----------------
__global__ __launch_bounds__(256, 2)
void gemm_qkv(const float* __restrict__ qin, const float* __restrict__ kin,
              const float* __restrict__ vin, const __bf16* __restrict__ Wcat,
              const float* __restrict__ bq, const float* __restrict__ bk,
              const float* __restrict__ bv,
              __bf16* __restrict__ Qh, __bf16* __restrict__ Kh,
              __bf16* __restrict__ Vt, float qscale)
{
  __shared__ __align__(16) __bf16 As[128 * 32];
  __shared__ __align__(16) __bf16 Bs[128 * 32];
  const int tid = threadIdx.x;
  const int wave = tid >> 6, lane = tid & 63;
  const int wr = wave >> 1, wc = wave & 1;
  const int r = lane & 15, hi = lane >> 4;
  const int lin = (int)blockIdx.y * 24 + (int)blockIdx.x;   // 0..1535
  const int xcd = lin & 7, s8 = lin >> 3;                   // s8: 0..191
  const int my = (xcd << 3) | (s8 / 24);                    // 0..63
  const int mx = s8 % 24;                                   // 0..23
  const int m0 = my * 128, n0 = mx * 128;
  const int proj = n0 >> 10;                       // block-uniform: 0=Q 1=K 2=V
  const float* Xa = proj == 0 ? qin : proj == 1 ? kin : vin;

  f32x4 acc[4][4] = {};

  for (int k0 = 0; k0 < Kdim; k0 += 32) {
    #pragma unroll
    for (int c = 0; c < 2; ++c) {
      int chunk = c * 256 + tid;
      int row = chunk >> 2;
      int cw = chunk & 3;
      int hc = cw ^ (row & 3);
      const float* src = Xa + (size_t)(m0 + row) * Kdim + k0 + hc * 8;
      float4 f0 = *(const float4*)src;
      float4 f1 = *(const float4*)(src + 4);
      union { __bf16 h[8]; uint4 u; } pk;
      pk.h[0] = (__bf16)f0.x; pk.h[1] = (__bf16)f0.y;
      pk.h[2] = (__bf16)f0.z; pk.h[3] = (__bf16)f0.w;
      pk.h[4] = (__bf16)f1.x; pk.h[5] = (__bf16)f1.y;
      pk.h[6] = (__bf16)f1.z; pk.h[7] = (__bf16)f1.w;
      *(uint4*)&As[(size_t)chunk * 8] = pk.u;
    }
    #pragma unroll
    for (int c = 0; c < 2; ++c) {
      int chunk = c * 256 + wave * 64 + lane;
      int row = chunk >> 2;
      int hc = (chunk & 3) ^ (row & 3);
      gload_lds16(Wcat + (size_t)(n0 + row) * Kdim + k0 + hc * 8,
                  &Bs[(size_t)(c * 256 + wave * 64) * 8]);
    }
    __syncthreads();
    bf16x8 af[4], bfr[4];
    #pragma unroll
    for (int m = 0; m < 4; ++m) {
      int rowl = wr * 64 + m * 16 + r;
      af[m] = *(const bf16x8*)&As[rowl * 32 + ((hi ^ (rowl & 3)) * 8)];
    }
    #pragma unroll
    for (int n = 0; n < 4; ++n) {
      int rowl = wc * 64 + n * 16 + r;
      bfr[n] = *(const bf16x8*)&Bs[rowl * 32 + ((hi ^ (rowl & 3)) * 8)];
    }
    #pragma unroll
    for (int m = 0; m < 4; ++m)
      #pragma unroll
      for (int n = 0; n < 4; ++n)
        acc[m][n] = __builtin_amdgcn_mfma_f32_16x16x32_bf16(af[m], bfr[n], acc[m][n], 0, 0, 0);
    __syncthreads();
  }

  const float* bias = proj == 0 ? bq : proj == 1 ? bk : bv;
  if (proj < 2) {
    __bf16* out = proj == 0 ? Qh : Kh;
    const float sc = proj == 0 ? qscale : 1.0f;
    #pragma unroll
    for (int m = 0; m < 4; ++m)
      #pragma unroll
      for (int n = 0; n < 4; ++n)
        #pragma unroll
        for (int rg = 0; rg < 4; ++rg) {
          int row_g = m0 + wr * 64 + m * 16 + hi * 4 + rg;
          int col_g = n0 + wc * 64 + n * 16 + r;
          int c = col_g & 1023, h = c >> 6, d = c & 63;
          int b = row_g >> 11, s = row_g & (Sc - 1);
          float v = (acc[m][n][rg] + bias[c]) * sc;
          out[((((size_t)b * Hc + h) * Sc + s) << 6) + d] = (__bf16)v;
        }
  } else {
    #pragma unroll
    for (int m = 0; m < 4; ++m)
      #pragma unroll
      for (int n = 0; n < 4; ++n) {
        int row0 = m0 + wr * 64 + m * 16 + hi * 4;
        int col_g = n0 + wc * 64 + n * 16 + r;
        int c = col_g & 1023, h = c >> 6, d = c & 63;
        int b = row0 >> 11, s = row0 & (Sc - 1);
        union { __bf16 hh[4]; uint2 u; } w;
        #pragma unroll
        for (int rg = 0; rg < 4; ++rg)
          w.hh[rg] = (__bf16)(acc[m][n][rg] + bias[c]);
        *(uint2*)&Vt[((((size_t)b * Hc + h) * HDc + d) << 11) + s] = w.u;
      }
  }
}

// ---------------- out-projection GEMM (R10-R21 proven) ----------------
__global__ __launch_bounds__(256, 2)
void gemm_out(const __bf16* __restrict__ A, const __bf16* __restrict__ Bw,
              const float* __restrict__ bias, float* __restrict__ outp)
{
  __shared__ __align__(16) __bf16 As[128 * 32];
  __shared__ __align__(16) __bf16 Bs[128 * 32];
  const int tid = threadIdx.x;
  const int wave = tid >> 6, lane = tid & 63;
  const int wr = wave >> 1, wc = wave & 1;
  const int r = lane & 15, hi = lane >> 4;
  const int lin = (int)blockIdx.y * 8 + (int)blockIdx.x;    // 0..511
  const int xcd = lin & 7, s8 = lin >> 3;                   // 0..63
  const int m0 = (((xcd << 3) | (s8 >> 3)) ) * 128;
  const int n0 = (s8 & 7) * 128;

  f32x4 acc[4][4] = {};

  for (int k0 = 0; k0 < Kdim; k0 += 32) {
    #pragma unroll
    for (int c = 0; c < 2; ++c) {
      int chunk = c * 256 + wave * 64 + lane;
      int row = chunk >> 2;
      int hc = (chunk & 3) ^ (row & 3);
      gload_lds16(A  + (size_t)(m0 + row) * Kdim + k0 + hc * 8,
                  &As[(size_t)(c * 256 + wave * 64) * 8]);
      gload_lds16(Bw + (size_t)(n0 + row) * Kdim + k0 + hc * 8,
                  &Bs[(size_t)(c * 256 + wave * 64) * 8]);
    }
    __syncthreads();
    bf16x8 af[4], bfr[4];
    #pragma unroll
    for (int m = 0; m < 4; ++m) {
      int rowl = wr * 64 + m * 16 + r;
      af[m] = *(const bf16x8*)&As[rowl * 32 + ((hi ^ (rowl & 3)) * 8)];
    }
    #pragma unroll
    for (int n = 0; n < 4; ++n) {
      int rowl = wc * 64 + n * 16 + r;
      bfr[n] = *(const bf16x8*)&Bs[rowl * 32 + ((hi ^ (rowl & 3)) * 8)];
    }
    #pragma unroll
    for (int m = 0; m < 4; ++m)
      #pragma unroll
      for (int n = 0; n < 4; ++n)
        acc[m][n] = __builtin_amdgcn_mfma_f32_16x16x32_bf16(af[m], bfr[n], acc[m][n], 0, 0, 0);
    __syncthreads();
  }

  #pragma unroll
  for (int m = 0; m < 4; ++m)
    #pragma unroll
    for (int n = 0; n < 4; ++n)
      #pragma unroll
      for (int rg = 0; rg < 4; ++rg) {
        int row_g = m0 + wr * 64 + m * 16 + hi * 4 + rg;
        int col_g = n0 + wc * 64 + n * 16 + r;
        outp[(size_t)row_g * Dc + col_g] = acc[m][n][rg] + bias[col_g];
      }
}

// ---------------- causal flash attention: 32x32 MFMA, lane-local softmax ----
// R21-proven body with the diagonal tile PEELED out of the loop: the main
// loop (t < T-1) has no diag test and unconditional prefetches; the last
// tile carries the causal mask and no prefetch. Arithmetic per tile is
// byte-identical; T==1 runs only the peeled tile on the preloaded data.
// NOTE (R18 lesson): keep shfl_xor(32) reductions; fused mov+permlane asm
// hits an unhandled cross-lane hazard (NaN).
__global__ __launch_bounds__(128, 2)
void attn_causal(const __bf16* __restrict__ Qh, const __bf16* __restrict__ Kh,
                 const __bf16* __restrict__ Vt, __bf16* __restrict__ outp)
{
  const int tid = threadIdx.x;
  const int wave = tid >> 6, lane = tid & 63;
  const int c32 = lane & 31;          // q-column / A-row index
  const int h5 = lane >> 5;           // half-wave
  // XCD swizzle (R10-proven): all 32 blocks of one bh on one XCD.
  const int lin = (int)blockIdx.y * 32 + (int)blockIdx.x;   // 0..2047
  const int xcd = lin & 7, s8 = lin >> 3;                   // s8: 0..255
  const int bh = (xcd << 3) | (s8 >> 5);                    // 0..63
  const int px = s8 & 31;                                   // 0..31
  const int qh = wave ? (63 - px) : px;                     // paired balance
  const int q0 = qh * 32;
  const __bf16* Q = Qh + (size_t)bh * (Sc * HDc);
  const __bf16* K = Kh + (size_t)bh * (Sc * HDc);
  const __bf16* V = Vt + (size_t)bh * (HDc * Sc);

  // Q B-operand frags: lane supplies B[k=8*h5+j][col=c32], d = dc*16+8*h5+j
  bf16x8 qf[4];
  #pragma unroll
  for (int dc = 0; dc < 4; ++dc)
    qf[dc] = *(const bf16x8*)&Q[(size_t)(q0 + c32) * 64 + dc * 16 + h5 * 8];

  f32x16 o0 = {}, o1 = {};    // O^T: col q=c32, row d=(reg&3)+8(reg>>2)+4h5 (+32)
  float mrow = -1e30f, lrow = 0.f;

  const int T = qh + 1;       // 32-kv tiles
  bf16x8 kf[4], vf0[2], vf1[2];

  // preload tile 0
  #pragma unroll
  for (int dc = 0; dc < 4; ++dc)
    kf[dc] = *(const bf16x8*)&K[(size_t)c32 * 64 + dc * 16 + h5 * 8];
  #pragma unroll
  for (int kc = 0; kc < 2; ++kc) {
    vf0[kc] = *(const bf16x8*)&V[(size_t)c32 * Sc + kc * 16 + h5 * 8];
    vf1[kc] = *(const bf16x8*)&V[(size_t)(32 + c32) * Sc + kc * 16 + h5 * 8];
  }

  // ---- main loop: non-diagonal tiles, unconditional prefetch ----
  for (int t = 0; t < T - 1; ++t) {
    const int kvn = (t + 1) * 32;

    f32x16 sn = {};
    sn = __builtin_amdgcn_mfma_f32_32x32x16_bf16(kf[0], qf[0], sn, 0, 0, 0);
    sn = __builtin_amdgcn_mfma_f32_32x32x16_bf16(kf[1], qf[1], sn, 0, 0, 0);
    sn = __builtin_amdgcn_mfma_f32_32x32x16_bf16(kf[2], qf[2], sn, 0, 0, 0);
    sn = __builtin_amdgcn_mfma_f32_32x32x16_bf16(kf[3], qf[3], sn, 0, 0, 0);

    // prefetch next K tile (kf dead after QK; softmax+pack cover latency)
    #pragma unroll
    for (int dc = 0; dc < 4; ++dc)
      kf[dc] = *(const bf16x8*)&K[(size_t)(kvn + c32) * 64 + dc * 16 + h5 * 8];

    // row-max: 15 in-lane + cross-half via proven shfl_xor(32)
    float mx = fmaxf(fmaxf(fmaxf(sn[0], sn[1]), fmaxf(sn[2], sn[3])),
                     fmaxf(fmaxf(sn[4], sn[5]), fmaxf(sn[6], sn[7])));
    mx = fmaxf(mx, fmaxf(fmaxf(fmaxf(sn[8], sn[9]), fmaxf(sn[10], sn[11])),
                         fmaxf(fmaxf(sn[12], sn[13]), fmaxf(sn[14], sn[15]))));
    mx = fmaxf(mx, __shfl_xor(mx, 32));
    if (__any(mx > mrow + 8.f)) {        // T13 defer-max (log2 domain)
      float mnew = fmaxf(mrow, mx);
      float sc = exp2_fast(mrow - mnew);
      lrow *= sc;
      o0 *= sc;
      o1 *= sc;
      mrow = mnew;
    }
    #pragma unroll
    for (int reg = 0; reg < 16; ++reg)
      sn[reg] = exp2_fast(sn[reg] - mrow);
    float t0s = (sn[0] + sn[1]) + (sn[2] + sn[3]);
    float t1s = (sn[4] + sn[5]) + (sn[6] + sn[7]);
    float t2s = (sn[8] + sn[9]) + (sn[10] + sn[11]);
    float t3s = (sn[12] + sn[13]) + (sn[14] + sn[15]);
    float rs = (t0s + t1s) + (t2s + t3s);
    rs += __shfl_xor(rs, 32);
    lrow += rs;

    // pack P -> B-operand: 8 cvt_pk + 4 permlane32_swap (distinct operands)
    uint32_t u0, u1, u2, u3, u4, u5, u6, u7;
    asm("v_cvt_pk_bf16_f32 %0, %1, %2" : "=v"(u0) : "v"(sn[0]),  "v"(sn[1]));
    asm("v_cvt_pk_bf16_f32 %0, %1, %2" : "=v"(u1) : "v"(sn[2]),  "v"(sn[3]));
    asm("v_cvt_pk_bf16_f32 %0, %1, %2" : "=v"(u2) : "v"(sn[4]),  "v"(sn[5]));
    asm("v_cvt_pk_bf16_f32 %0, %1, %2" : "=v"(u3) : "v"(sn[6]),  "v"(sn[7]));
    asm("v_cvt_pk_bf16_f32 %0, %1, %2" : "=v"(u4) : "v"(sn[8]),  "v"(sn[9]));
    asm("v_cvt_pk_bf16_f32 %0, %1, %2" : "=v"(u5) : "v"(sn[10]), "v"(sn[11]));
    asm("v_cvt_pk_bf16_f32 %0, %1, %2" : "=v"(u6) : "v"(sn[12]), "v"(sn[13]));
    asm("v_cvt_pk_bf16_f32 %0, %1, %2" : "=v"(u7) : "v"(sn[14]), "v"(sn[15]));
    asm("v_permlane32_swap_b32 %0, %1" : "+v"(u0), "+v"(u2));
    asm("v_permlane32_swap_b32 %0, %1" : "+v"(u1), "+v"(u3));
    asm("v_permlane32_swap_b32 %0, %1" : "+v"(u4), "+v"(u6));
    asm("v_permlane32_swap_b32 %0, %1" : "+v"(u5), "+v"(u7));
    union { uint32_t w[4]; bf16x8 v; } pb0, pb1;
    pb0.w[0] = u0; pb0.w[1] = u1; pb0.w[2] = u2; pb0.w[3] = u3;  // kv 0..15
    pb1.w[0] = u4; pb1.w[1] = u5; pb1.w[2] = u6; pb1.w[3] = u7;  // kv 16..31

    // ---- PV: O^T += V^T-frag * P-frag ----
    o0 = __builtin_amdgcn_mfma_f32_32x32x16_bf16(vf0[0], pb0.v, o0, 0, 0, 0);
    o0 = __builtin_amdgcn_mfma_f32_32x32x16_bf16(vf0[1], pb1.v, o0, 0, 0, 0);
    o1 = __builtin_amdgcn_mfma_f32_32x32x16_bf16(vf1[0], pb0.v, o1, 0, 0, 0);
    o1 = __builtin_amdgcn_mfma_f32_32x32x16_bf16(vf1[1], pb1.v, o1, 0, 0, 0);

    // prefetch next V tile (vf dead after PV)
    #pragma unroll
    for (int kc = 0; kc < 2; ++kc) {
      vf0[kc] = *(const bf16x8*)&V[(size_t)c32 * Sc + kvn + kc * 16 + h5 * 8];
      vf1[kc] = *(const bf16x8*)&V[(size_t)(32 + c32) * Sc + kvn + kc * 16 + h5 * 8];
    }
  }

  // ---- peeled diagonal tile (t = T-1): causal mask, no prefetch ----
  {
    f32x16 sn = {};
    sn = __builtin_amdgcn_mfma_f32_32x32x16_bf16(kf[0], qf[0], sn, 0, 0, 0);
    sn = __builtin_amdgcn_mfma_f32_32x32x16_bf16(kf[1], qf[1], sn, 0, 0, 0);
    sn = __builtin_amdgcn_mfma_f32_32x32x16_bf16(kf[2], qf[2], sn, 0, 0, 0);
    sn = __builtin_amdgcn_mfma_f32_32x32x16_bf16(kf[3], qf[3], sn, 0, 0, 0);

    #pragma unroll
    for (int reg = 0; reg < 16; ++reg)
      if ((reg & 3) + 8 * (reg >> 2) + 4 * h5 > c32) sn[reg] = -1e30f;

    float mx = fmaxf(fmaxf(fmaxf(sn[0], sn[1]), fmaxf(sn[2], sn[3])),
                     fmaxf(fmaxf(sn[4], sn[5]), fmaxf(sn[6], sn[7])));
    mx = fmaxf(mx, fmaxf(fmaxf(fmaxf(sn[8], sn[9]), fmaxf(sn[10], sn[11])),
                         fmaxf(fmaxf(sn[12], sn[13]), fmaxf(sn[14], sn[15]))));
    mx = fmaxf(mx, __shfl_xor(mx, 32));
    if (__any(mx > mrow + 8.f)) {
      float mnew = fmaxf(mrow, mx);
      float sc = exp2_fast(mrow - mnew);
      lrow *= sc;
      o0 *= sc;
      o1 *= sc;
      mrow = mnew;
    }
    #pragma unroll
    for (int reg = 0; reg < 16; ++reg)
      sn[reg] = exp2_fast(sn[reg] - mrow);
    float t0s = (sn[0] + sn[1]) + (sn[2] + sn[3]);
    float t1s = (sn[4] + sn[5]) + (sn[6] + sn[7]);
    float t2s = (sn[8] + sn[9]) + (sn[10] + sn[11]);
    float t3s = (sn[12] + sn[13]) + (sn[14] + sn[15]);
    float rs = (t0s + t1s) + (t2s + t3s);
    rs += __shfl_xor(rs, 32);
    lrow += rs;

    uint32_t u0, u1, u2, u3, u4, u5, u6, u7;
    asm("v_cvt_pk_bf16_f32 %0, %1, %2" : "=v"(u0) : "v"(sn[0]),  "v"(sn[1]));
    asm("v_cvt_pk_bf16_f32 %0, %1, %2" : "=v"(u1) : "v"(sn[2]),  "v"(sn[3]));
    asm("v_cvt_pk_bf16_f32 %0, %1, %2" : "=v"(u2) : "v"(sn[4]),  "v"(sn[5]));
    asm("v_cvt_pk_bf16_f32 %0, %1, %2" : "=v"(u3) : "v"(sn[6]),  "v"(sn[7]));
    asm("v_cvt_pk_bf16_f32 %0, %1, %2" : "=v"(u4) : "v"(sn[8]),  "v"(sn[9]));
    asm("v_cvt_pk_bf16_f32 %0, %1, %2" : "=v"(u5) : "v"(sn[10]), "v"(sn[11]));
    asm("v_cvt_pk_bf16_f32 %0, %1, %2" : "=v"(u6) : "v"(sn[12]), "v"(sn[13]));
    asm("v_cvt_pk_bf16_f32 %0, %1, %2" : "=v"(u7) : "v"(sn[14]), "v"(sn[15]));
    asm("v_permlane32_swap_b32 %0, %1" : "+v"(u0), "+v"(u2));
    asm("v_permlane32_swap_b32 %0, %1" : "+v"(u1), "+v"(u3));
    asm("v_permlane32_swap_b32 %0, %1" : "+v"(u4), "+v"(u6));
    asm("v_permlane32_swap_b32 %0, %1" : "+v"(u5), "+v"(u7));
    union { uint32_t w[4]; bf16x8 v; } pb0, pb1;
    pb0.w[0] = u0; pb0.w[1] = u1; pb0.w[2] = u2; pb0.w[3] = u3;
    pb1.w[0] = u4; pb1.w[1] = u5; pb1.w[2] = u6; pb1.w[3] = u7;

    o0 = __builtin_amdgcn_mfma_f32_32x32x16_bf16(vf0[0], pb0.v, o0, 0, 0, 0);
    o0 = __builtin_amdgcn_mfma_f32_32x32x16_bf16(vf0[1], pb1.v, o0, 0, 0, 0);
    o1 = __builtin_amdgcn_mfma_f32_32x32x16_bf16(vf1[0], pb0.v, o1, 0, 0, 0);
    o1 = __builtin_amdgcn_mfma_f32_32x32x16_bf16(vf1[1], pb1.v, o1, 0, 0, 0);
  }

  // ---- epilogue: all of a lane's outputs share q-col c32 -> one scalar inv ----
  const int b = bh >> 4, h = bh & 15;
  const float inv = 1.f / lrow;
  __bf16* obase = outp + ((size_t)b * Sc + q0 + c32) * Dc + h * 64;
  #pragma unroll
  for (int rq = 0; rq < 4; ++rq) {               // d = rr + 8*rq + 4*h5
    union { __bf16 hh[4]; uint2 u; } w;
    #pragma unroll
    for (int rr = 0; rr < 4; ++rr) w.hh[rr] = (__bf16)(o0[rq * 4 + rr] * inv);
    *(uint2*)&obase[rq * 8 + h5 * 4] = w.u;
  }
  #pragma unroll
  for (int rq = 0; rq < 4; ++rq) {               // d = 32 + rr + 8*rq + 4*h5
    union { __bf16 hh[4]; uint2 u; } w;
    #pragma unroll
    for (int rr = 0; rr < 4; ++rr) w.hh[rr] = (__bf16)(o1[rq * 4 + rr] * inv);
    *(uint2*)&obase[32 + rq * 8 + h5 * 4] = w.u;
  }
}

// ---------------- launch ----------------
extern "C" void kernel_launch(void* const* d_in, const int* in_sizes, int n_in,
                              void* d_out, int out_size, void* d_ws, size_t ws_size,
                              hipStream_t stream) {
  const float* q  = (const float*)d_in[0];
  const float* k  = (const float*)d_in[1];
  const float* v  = (const float*)d_in[2];
  const float* Wq = (const float*)d_in[4];
  const float* bq = (const float*)d_in[5];
  const float* Wk = (const float*)d_in[6];
  const float* bk = (const float*)d_in[7];
  const float* Wv = (const float*)d_in[8];
  const float* bv = (const float*)d_in[9];
  const float* Wo = (const float*)d_in[10];
  const float* bo = (const float*)d_in[11];

  char* ws = (char*)d_ws;
  constexpr size_t MB = 1u << 20;
  __bf16* Wcat = (__bf16*)(ws + 0 * MB);   // Wq|Wk|Wv rows, 6 MB
  __bf16* Wkb  = (__bf16*)(ws + 2 * MB);
  __bf16* Wvb  = (__bf16*)(ws + 4 * MB);
  __bf16* Wob  = (__bf16*)(ws + 6 * MB);
  __bf16* Xbf  = (__bf16*)(ws + 8 * MB);   // attn out, 16 MB
  __bf16* QhB  = (__bf16*)(ws + 24 * MB);
  __bf16* KhB  = (__bf16*)(ws + 40 * MB);
  __bf16* VtB  = (__bf16*)(ws + 56 * MB);  // V^T: [B*H][64][S]

  const int nW4 = (Dc * Dc) / 4;           // 262144
  cvt4_f32_to_bf16<<<(4 * nW4) / 256, 256, 0, stream>>>(Wq, Wk, Wv, Wo, Wcat, Wkb, Wvb, Wob, nW4);

  const float qscale = 0.125f * 1.44269504f;  // fold 1/sqrt(64) and log2(e)
  gemm_qkv<<<dim3(24, Mrows / 128), 256, 0, stream>>>(q, k, v, Wcat, bq, bk, bv,
                                                      QhB, KhB, VtB, qscale);

  attn_causal<<<dim3(32, Bc * Hc), 128, 0, stream>>>(QhB, KhB, VtB, Xbf);

  gemm_out<<<dim3(8, Mrows / 128), 256, 0, stream>>>(Xbf, Wob, bo, (float*)d_out);
}

// Round 23
// 235.393 us; speedup vs baseline: 1.1547x; 1.1547x over previous
//
#include <hip/hip_runtime.h>
#include <hip/hip_bf16.h>
#include <cstdint>
#include <cstddef>

typedef __attribute__((ext_vector_type(4))) float f32x4;
typedef __attribute__((ext_vector_type(16))) float f32x16;
typedef __attribute__((ext_vector_type(8))) __bf16 bf16x8;

constexpr int Bc = 4, Sc = 2048, Dc = 1024, Hc = 16, HDc = 64;
constexpr int Mrows = Bc * Sc;   // 8192
constexpr int Kdim = Dc;         // 1024

__device__ __forceinline__ void gload_lds16(const void* g, void* lds) {
  __builtin_amdgcn_global_load_lds(
      (const __attribute__((address_space(1))) void*)g,
      (__attribute__((address_space(3))) void*)lds, 16, 0, 0);
}

// bare v_exp_f32 (= exp2) — numerically validated R13/R15/R20/R21. Inputs bounded
// above by defer-max; large-negative underflows to 0 (softmax semantics).
__device__ __forceinline__ float exp2_fast(float x) {
  float r;
  asm("v_exp_f32 %0, %1" : "=v"(r) : "v"(x));
  return r;
}

// ---------------- fp32 -> bf16 weight converts (one fused launch) ----------------
__global__ void cvt4_f32_to_bf16(const float* __restrict__ s0, const float* __restrict__ s1,
                                 const float* __restrict__ s2, const float* __restrict__ s3,
                                 __bf16* __restrict__ d0, __bf16* __restrict__ d1,
                                 __bf16* __restrict__ d2, __bf16* __restrict__ d3, int n4each) {
  int i = blockIdx.x * blockDim.x + threadIdx.x;
  int which = i / n4each, j = i - which * n4each;
  const float* s = which == 0 ? s0 : which == 1 ? s1 : which == 2 ? s2 : s3;
  __bf16* d = which == 0 ? d0 : which == 1 ? d1 : which == 2 ? d2 : d3;
  float4 f = ((const float4*)s)[j];
  union { __bf16 h[4]; uint2 u; } p;
  p.h[0] = (__bf16)f.x; p.h[1] = (__bf16)f.y;
  p.h[2] = (__bf16)f.z; p.h[3] = (__bf16)f.w;
  ((uint2*)d)[j] = p.u;
}

// ---------------- fused QKV GEMM (R10-R21 proven) ----------------
__global__ __launch_bounds__(256, 2)
void gemm_qkv(const float* __restrict__ qin, const float* __restrict__ kin,
              const float* __restrict__ vin, const __bf16* __restrict__ Wcat,
              const float* __restrict__ bq, const float* __restrict__ bk,
              const float* __restrict__ bv,
              __bf16* __restrict__ Qh, __bf16* __restrict__ Kh,
              __bf16* __restrict__ Vt, float qscale)
{
  __shared__ __align__(16) __bf16 As[128 * 32];
  __shared__ __align__(16) __bf16 Bs[128 * 32];
  const int tid = threadIdx.x;
  const int wave = tid >> 6, lane = tid & 63;
  const int wr = wave >> 1, wc = wave & 1;
  const int r = lane & 15, hi = lane >> 4;
  const int lin = (int)blockIdx.y * 24 + (int)blockIdx.x;   // 0..1535
  const int xcd = lin & 7, s8 = lin >> 3;                   // s8: 0..191
  const int my = (xcd << 3) | (s8 / 24);                    // 0..63
  const int mx = s8 % 24;                                   // 0..23
  const int m0 = my * 128, n0 = mx * 128;
  const int proj = n0 >> 10;                       // block-uniform: 0=Q 1=K 2=V
  const float* Xa = proj == 0 ? qin : proj == 1 ? kin : vin;

  f32x4 acc[4][4] = {};

  for (int k0 = 0; k0 < Kdim; k0 += 32) {
    #pragma unroll
    for (int c = 0; c < 2; ++c) {
      int chunk = c * 256 + tid;
      int row = chunk >> 2;
      int cw = chunk & 3;
      int hc = cw ^ (row & 3);
      const float* src = Xa + (size_t)(m0 + row) * Kdim + k0 + hc * 8;
      float4 f0 = *(const float4*)src;
      float4 f1 = *(const float4*)(src + 4);
      union { __bf16 h[8]; uint4 u; } pk;
      pk.h[0] = (__bf16)f0.x; pk.h[1] = (__bf16)f0.y;
      pk.h[2] = (__bf16)f0.z; pk.h[3] = (__bf16)f0.w;
      pk.h[4] = (__bf16)f1.x; pk.h[5] = (__bf16)f1.y;
      pk.h[6] = (__bf16)f1.z; pk.h[7] = (__bf16)f1.w;
      *(uint4*)&As[(size_t)chunk * 8] = pk.u;
    }
    #pragma unroll
    for (int c = 0; c < 2; ++c) {
      int chunk = c * 256 + wave * 64 + lane;
      int row = chunk >> 2;
      int hc = (chunk & 3) ^ (row & 3);
      gload_lds16(Wcat + (size_t)(n0 + row) * Kdim + k0 + hc * 8,
                  &Bs[(size_t)(c * 256 + wave * 64) * 8]);
    }
    __syncthreads();
    bf16x8 af[4], bfr[4];
    #pragma unroll
    for (int m = 0; m < 4; ++m) {
      int rowl = wr * 64 + m * 16 + r;
      af[m] = *(const bf16x8*)&As[rowl * 32 + ((hi ^ (rowl & 3)) * 8)];
    }
    #pragma unroll
    for (int n = 0; n < 4; ++n) {
      int rowl = wc * 64 + n * 16 + r;
      bfr[n] = *(const bf16x8*)&Bs[rowl * 32 + ((hi ^ (rowl & 3)) * 8)];
    }
    #pragma unroll
    for (int m = 0; m < 4; ++m)
      #pragma unroll
      for (int n = 0; n < 4; ++n)
        acc[m][n] = __builtin_amdgcn_mfma_f32_16x16x32_bf16(af[m], bfr[n], acc[m][n], 0, 0, 0);
    __syncthreads();
  }

  const float* bias = proj == 0 ? bq : proj == 1 ? bk : bv;
  if (proj < 2) {
    __bf16* out = proj == 0 ? Qh : Kh;
    const float sc = proj == 0 ? qscale : 1.0f;
    #pragma unroll
    for (int m = 0; m < 4; ++m)
      #pragma unroll
      for (int n = 0; n < 4; ++n)
        #pragma unroll
        for (int rg = 0; rg < 4; ++rg) {
          int row_g = m0 + wr * 64 + m * 16 + hi * 4 + rg;
          int col_g = n0 + wc * 64 + n * 16 + r;
          int c = col_g & 1023, h = c >> 6, d = c & 63;
          int b = row_g >> 11, s = row_g & (Sc - 1);
          float v = (acc[m][n][rg] + bias[c]) * sc;
          out[((((size_t)b * Hc + h) * Sc + s) << 6) + d] = (__bf16)v;
        }
  } else {
    #pragma unroll
    for (int m = 0; m < 4; ++m)
      #pragma unroll
      for (int n = 0; n < 4; ++n) {
        int row0 = m0 + wr * 64 + m * 16 + hi * 4;
        int col_g = n0 + wc * 64 + n * 16 + r;
        int c = col_g & 1023, h = c >> 6, d = c & 63;
        int b = row0 >> 11, s = row0 & (Sc - 1);
        union { __bf16 hh[4]; uint2 u; } w;
        #pragma unroll
        for (int rg = 0; rg < 4; ++rg)
          w.hh[rg] = (__bf16)(acc[m][n][rg] + bias[c]);
        *(uint2*)&Vt[((((size_t)b * Hc + h) * HDc + d) << 11) + s] = w.u;
      }
  }
}

// ---------------- out-projection GEMM (R10-R21 proven) ----------------
__global__ __launch_bounds__(256, 2)
void gemm_out(const __bf16* __restrict__ A, const __bf16* __restrict__ Bw,
              const float* __restrict__ bias, float* __restrict__ outp)
{
  __shared__ __align__(16) __bf16 As[128 * 32];
  __shared__ __align__(16) __bf16 Bs[128 * 32];
  const int tid = threadIdx.x;
  const int wave = tid >> 6, lane = tid & 63;
  const int wr = wave >> 1, wc = wave & 1;
  const int r = lane & 15, hi = lane >> 4;
  const int lin = (int)blockIdx.y * 8 + (int)blockIdx.x;    // 0..511
  const int xcd = lin & 7, s8 = lin >> 3;                   // 0..63
  const int m0 = (((xcd << 3) | (s8 >> 3)) ) * 128;
  const int n0 = (s8 & 7) * 128;

  f32x4 acc[4][4] = {};

  for (int k0 = 0; k0 < Kdim; k0 += 32) {
    #pragma unroll
    for (int c = 0; c < 2; ++c) {
      int chunk = c * 256 + wave * 64 + lane;
      int row = chunk >> 2;
      int hc = (chunk & 3) ^ (row & 3);
      gload_lds16(A  + (size_t)(m0 + row) * Kdim + k0 + hc * 8,
                  &As[(size_t)(c * 256 + wave * 64) * 8]);
      gload_lds16(Bw + (size_t)(n0 + row) * Kdim + k0 + hc * 8,
                  &Bs[(size_t)(c * 256 + wave * 64) * 8]);
    }
    __syncthreads();
    bf16x8 af[4], bfr[4];
    #pragma unroll
    for (int m = 0; m < 4; ++m) {
      int rowl = wr * 64 + m * 16 + r;
      af[m] = *(const bf16x8*)&As[rowl * 32 + ((hi ^ (rowl & 3)) * 8)];
    }
    #pragma unroll
    for (int n = 0; n < 4; ++n) {
      int rowl = wc * 64 + n * 16 + r;
      bfr[n] = *(const bf16x8*)&Bs[rowl * 32 + ((hi ^ (rowl & 3)) * 8)];
    }
    #pragma unroll
    for (int m = 0; m < 4; ++m)
      #pragma unroll
      for (int n = 0; n < 4; ++n)
        acc[m][n] = __builtin_amdgcn_mfma_f32_16x16x32_bf16(af[m], bfr[n], acc[m][n], 0, 0, 0);
    __syncthreads();
  }

  #pragma unroll
  for (int m = 0; m < 4; ++m)
    #pragma unroll
    for (int n = 0; n < 4; ++n)
      #pragma unroll
      for (int rg = 0; rg < 4; ++rg) {
        int row_g = m0 + wr * 64 + m * 16 + hi * 4 + rg;
        int col_g = n0 + wc * 64 + n * 16 + r;
        outp[(size_t)row_g * Dc + col_g] = acc[m][n][rg] + bias[col_g];
      }
}

// ---------------- causal flash attention: 32x32 MFMA, lane-local softmax ----
// R21-proven body (session best: 137 us attn / 235.5 us total). Wave owns 32
// q-rows + full causal KV range; wave0 qh=px / wave1 qh=63-px (per-CU work
// perfectly equal). Single loop with in-loop diag test (R22 peel regressed:
// code duplication perturbs regalloc/scheduling, +8 VGPR, -25% perf).
// NOTE (R18 lesson): keep shfl_xor(32) reductions; fused mov+permlane asm
// hits an unhandled cross-lane hazard (NaN).
__global__ __launch_bounds__(128, 2)
void attn_causal(const __bf16* __restrict__ Qh, const __bf16* __restrict__ Kh,
                 const __bf16* __restrict__ Vt, __bf16* __restrict__ outp)
{
  const int tid = threadIdx.x;
  const int wave = tid >> 6, lane = tid & 63;
  const int c32 = lane & 31;          // q-column / A-row index
  const int h5 = lane >> 5;           // half-wave
  // XCD swizzle (R10-proven): all 32 blocks of one bh on one XCD.
  const int lin = (int)blockIdx.y * 32 + (int)blockIdx.x;   // 0..2047
  const int xcd = lin & 7, s8 = lin >> 3;                   // s8: 0..255
  const int bh = (xcd << 3) | (s8 >> 5);                    // 0..63
  const int px = s8 & 31;                                   // 0..31
  const int qh = wave ? (63 - px) : px;                     // paired balance
  const int q0 = qh * 32;
  const __bf16* Q = Qh + (size_t)bh * (Sc * HDc);
  const __bf16* K = Kh + (size_t)bh * (Sc * HDc);
  const __bf16* V = Vt + (size_t)bh * (HDc * Sc);

  // Q B-operand frags: lane supplies B[k=8*h5+j][col=c32], d = dc*16+8*h5+j
  bf16x8 qf[4];
  #pragma unroll
  for (int dc = 0; dc < 4; ++dc)
    qf[dc] = *(const bf16x8*)&Q[(size_t)(q0 + c32) * 64 + dc * 16 + h5 * 8];

  f32x16 o0 = {}, o1 = {};    // O^T: col q=c32, row d=(reg&3)+8(reg>>2)+4h5 (+32)
  float mrow = -1e30f, lrow = 0.f;

  const int T = qh + 1;       // 32-kv tiles
  bf16x8 kf[4], vf0[2], vf1[2];

  // preload tile 0
  #pragma unroll
  for (int dc = 0; dc < 4; ++dc)
    kf[dc] = *(const bf16x8*)&K[(size_t)c32 * 64 + dc * 16 + h5 * 8];
  #pragma unroll
  for (int kc = 0; kc < 2; ++kc) {
    vf0[kc] = *(const bf16x8*)&V[(size_t)c32 * Sc + kc * 16 + h5 * 8];
    vf1[kc] = *(const bf16x8*)&V[(size_t)(32 + c32) * Sc + kc * 16 + h5 * 8];
  }

  for (int t = 0; t < T; ++t) {
    const bool diag = (t == T - 1);
    const int kvn = (t + 1) * 32;

    // ---- QK^T: S^T[kv][q] over one 32x32 tile, K=64 via 4 chained MFMAs ----
    f32x16 sn = {};
    sn = __builtin_amdgcn_mfma_f32_32x32x16_bf16(kf[0], qf[0], sn, 0, 0, 0);
    sn = __builtin_amdgcn_mfma_f32_32x32x16_bf16(kf[1], qf[1], sn, 0, 0, 0);
    sn = __builtin_amdgcn_mfma_f32_32x32x16_bf16(kf[2], qf[2], sn, 0, 0, 0);
    sn = __builtin_amdgcn_mfma_f32_32x32x16_bf16(kf[3], qf[3], sn, 0, 0, 0);

    // prefetch next K tile NOW (kf dead after QK; softmax+pack cover latency)
    if (t + 1 < T) {
      #pragma unroll
      for (int dc = 0; dc < 4; ++dc)
        kf[dc] = *(const bf16x8*)&K[(size_t)(kvn + c32) * 64 + dc * 16 + h5 * 8];
    }

    if (diag) {
      #pragma unroll
      for (int reg = 0; reg < 16; ++reg)
        if ((reg & 3) + 8 * (reg >> 2) + 4 * h5 > c32) sn[reg] = -1e30f;
    }

    // row-max: 15 in-lane + cross-half via proven shfl_xor(32)
    float mx = fmaxf(fmaxf(fmaxf(sn[0], sn[1]), fmaxf(sn[2], sn[3])),
                     fmaxf(fmaxf(sn[4], sn[5]), fmaxf(sn[6], sn[7])));
    mx = fmaxf(mx, fmaxf(fmaxf(fmaxf(sn[8], sn[9]), fmaxf(sn[10], sn[11])),
                         fmaxf(fmaxf(sn[12], sn[13]), fmaxf(sn[14], sn[15]))));
    mx = fmaxf(mx, __shfl_xor(mx, 32));
    if (__any(mx > mrow + 8.f)) {        // T13 defer-max (log2 domain)
      float mnew = fmaxf(mrow, mx);
      float sc = exp2_fast(mrow - mnew);
      lrow *= sc;
      o0 *= sc;
      o1 *= sc;
      mrow = mnew;
    }
    #pragma unroll
    for (int reg = 0; reg < 16; ++reg)
      sn[reg] = exp2_fast(sn[reg] - mrow);
    // balanced tree sum (reassociation only)
    float t0s = (sn[0] + sn[1]) + (sn[2] + sn[3]);
    float t1s = (sn[4] + sn[5]) + (sn[6] + sn[7]);
    float t2s = (sn[8] + sn[9]) + (sn[10] + sn[11]);
    float t3s = (sn[12] + sn[13]) + (sn[14] + sn[15]);
    float rs = (t0s + t1s) + (t2s + t3s);
    rs += __shfl_xor(rs, 32);
    lrow += rs;

    // pack P -> B-operand: 8 cvt_pk + 4 permlane32_swap (distinct operands)
    uint32_t u0, u1, u2, u3, u4, u5, u6, u7;
    asm("v_cvt_pk_bf16_f32 %0, %1, %2" : "=v"(u0) : "v"(sn[0]),  "v"(sn[1]));
    asm("v_cvt_pk_bf16_f32 %0, %1, %2" : "=v"(u1) : "v"(sn[2]),  "v"(sn[3]));
    asm("v_cvt_pk_bf16_f32 %0, %1, %2" : "=v"(u2) : "v"(sn[4]),  "v"(sn[5]));
    asm("v_cvt_pk_bf16_f32 %0, %1, %2" : "=v"(u3) : "v"(sn[6]),  "v"(sn[7]));
    asm("v_cvt_pk_bf16_f32 %0, %1, %2" : "=v"(u4) : "v"(sn[8]),  "v"(sn[9]));
    asm("v_cvt_pk_bf16_f32 %0, %1, %2" : "=v"(u5) : "v"(sn[10]), "v"(sn[11]));
    asm("v_cvt_pk_bf16_f32 %0, %1, %2" : "=v"(u6) : "v"(sn[12]), "v"(sn[13]));
    asm("v_cvt_pk_bf16_f32 %0, %1, %2" : "=v"(u7) : "v"(sn[14]), "v"(sn[15]));
    asm("v_permlane32_swap_b32 %0, %1" : "+v"(u0), "+v"(u2));
    asm("v_permlane32_swap_b32 %0, %1" : "+v"(u1), "+v"(u3));
    asm("v_permlane32_swap_b32 %0, %1" : "+v"(u4), "+v"(u6));
    asm("v_permlane32_swap_b32 %0, %1" : "+v"(u5), "+v"(u7));
    union { uint32_t w[4]; bf16x8 v; } pb0, pb1;
    pb0.w[0] = u0; pb0.w[1] = u1; pb0.w[2] = u2; pb0.w[3] = u3;  // kv 0..15
    pb1.w[0] = u4; pb1.w[1] = u5; pb1.w[2] = u6; pb1.w[3] = u7;  // kv 16..31

    // ---- PV: O^T += V^T-frag * P-frag ----
    o0 = __builtin_amdgcn_mfma_f32_32x32x16_bf16(vf0[0], pb0.v, o0, 0, 0, 0);
    o0 = __builtin_amdgcn_mfma_f32_32x32x16_bf16(vf0[1], pb1.v, o0, 0, 0, 0);
    o1 = __builtin_amdgcn_mfma_f32_32x32x16_bf16(vf1[0], pb0.v, o1, 0, 0, 0);
    o1 = __builtin_amdgcn_mfma_f32_32x32x16_bf16(vf1[1], pb1.v, o1, 0, 0, 0);

    // prefetch next V tile (vf dead after PV)
    if (t + 1 < T) {
      #pragma unroll
      for (int kc = 0; kc < 2; ++kc) {
        vf0[kc] = *(const bf16x8*)&V[(size_t)c32 * Sc + kvn + kc * 16 + h5 * 8];
        vf1[kc] = *(const bf16x8*)&V[(size_t)(32 + c32) * Sc + kvn + kc * 16 + h5 * 8];
      }
    }
  }

  // ---- epilogue: all of a lane's outputs share q-col c32 -> one scalar inv ----
  const int b = bh >> 4, h = bh & 15;
  const float inv = 1.f / lrow;
  __bf16* obase = outp + ((size_t)b * Sc + q0 + c32) * Dc + h * 64;
  #pragma unroll
  for (int rq = 0; rq < 4; ++rq) {               // d = rr + 8*rq + 4*h5
    union { __bf16 hh[4]; uint2 u; } w;
    #pragma unroll
    for (int rr = 0; rr < 4; ++rr) w.hh[rr] = (__bf16)(o0[rq * 4 + rr] * inv);
    *(uint2*)&obase[rq * 8 + h5 * 4] = w.u;
  }
  #pragma unroll
  for (int rq = 0; rq < 4; ++rq) {               // d = 32 + rr + 8*rq + 4*h5
    union { __bf16 hh[4]; uint2 u; } w;
    #pragma unroll
    for (int rr = 0; rr < 4; ++rr) w.hh[rr] = (__bf16)(o1[rq * 4 + rr] * inv);
    *(uint2*)&obase[32 + rq * 8 + h5 * 4] = w.u;
  }
}

// ---------------- launch ----------------
extern "C" void kernel_launch(void* const* d_in, const int* in_sizes, int n_in,
                              void* d_out, int out_size, void* d_ws, size_t ws_size,
                              hipStream_t stream) {
  const float* q  = (const float*)d_in[0];
  const float* k  = (const float*)d_in[1];
  const float* v  = (const float*)d_in[2];
  const float* Wq = (const float*)d_in[4];
  const float* bq = (const float*)d_in[5];
  const float* Wk = (const float*)d_in[6];
  const float* bk = (const float*)d_in[7];
  const float* Wv = (const float*)d_in[8];
  const float* bv = (const float*)d_in[9];
  const float* Wo = (const float*)d_in[10];
  const float* bo = (const float*)d_in[11];

  char* ws = (char*)d_ws;
  constexpr size_t MB = 1u << 20;
  __bf16* Wcat = (__bf16*)(ws + 0 * MB);   // Wq|Wk|Wv rows, 6 MB
  __bf16* Wkb  = (__bf16*)(ws + 2 * MB);
  __bf16* Wvb  = (__bf16*)(ws + 4 * MB);
  __bf16* Wob  = (__bf16*)(ws + 6 * MB);
  __bf16* Xbf  = (__bf16*)(ws + 8 * MB);   // attn out, 16 MB
  __bf16* QhB  = (__bf16*)(ws + 24 * MB);
  __bf16* KhB  = (__bf16*)(ws + 40 * MB);
  __bf16* VtB  = (__bf16*)(ws + 56 * MB);  // V^T: [B*H][64][S]

  const int nW4 = (Dc * Dc) / 4;           // 262144
  cvt4_f32_to_bf16<<<(4 * nW4) / 256, 256, 0, stream>>>(Wq, Wk, Wv, Wo, Wcat, Wkb, Wvb, Wob, nW4);

  const float qscale = 0.125f * 1.44269504f;  // fold 1/sqrt(64) and log2(e)
  gemm_qkv<<<dim3(24, Mrows / 128), 256, 0, stream>>>(q, k, v, Wcat, bq, bk, bv,
                                                      QhB, KhB, VtB, qscale);

  attn_causal<<<dim3(32, Bc * Hc), 128, 0, stream>>>(QhB, KhB, VtB, Xbf);

  gemm_out<<<dim3(8, Mrows / 128), 256, 0, stream>>>(Xbf, Wob, bo, (float*)d_out);
}